// Round 11
// baseline (91.908 us; speedup 1.0000x reference)
//
#include <hip/hip_runtime.h>
#include <math.h>

#define B_ 8
#define C_ 128
#define N_ 64
#define T_ 512
#define H_ 4
#define D_ 32
#define OUT_ 128
#define E_ 256
#define EP_ 320   // E + N self-loops
#define NEG_SLOPE 0.2f
#define BN_EPS 1e-5f
#define TCK 32    // time steps per block: rows are 128 B -> full-line misses
#define NT_ (N_ * T_)

#define FMA4(A, X, S) \
  A.x = fmaf(X.x, S, A.x); A.y = fmaf(X.y, S, A.y); \
  A.z = fmaf(X.z, S, A.z); A.w = fmaf(X.w, S, A.w);

// ---- setup: wa[c][8] = W·att; in-list (src per in-edge, grouped by dst);
// ----        out-list (dst per out-edge, grouped by src)
__global__ void setup_kernel(const float* __restrict__ W,
                             const float* __restrict__ att_src,
                             const float* __restrict__ att_dst,
                             const int* __restrict__ edge_index,
                             float* __restrict__ wa,
                             int* __restrict__ iOff_g, int* __restrict__ iSrc_g,
                             int* __restrict__ oOff_g, int* __restrict__ oDst_g) {
  __shared__ int icnt[N_], ibase[N_ + 1], ifill[N_];
  __shared__ int ocnt[N_], obase[N_ + 1], ofill[N_];
  __shared__ int esrc[EP_], edst[EP_];
  int tid = threadIdx.x;

  for (int idx = tid; idx < C_ * 8; idx += blockDim.x) {
    int c = idx >> 3, j = idx & 7, h = j & 3;
    const float* att = (j < 4) ? att_src : att_dst;
    float s = 0.f;
    for (int d = 0; d < D_; ++d)
      s += W[(c * H_ + h) * D_ + d] * att[h * D_ + d];
    wa[idx] = s;
  }
  if (tid < N_) { icnt[tid] = 0; ifill[tid] = 0; ocnt[tid] = 0; ofill[tid] = 0; }
  __syncthreads();
  for (int e = tid; e < EP_; e += blockDim.x) {
    int s, d;
    if (e < E_) { s = edge_index[e]; d = edge_index[E_ + e]; }
    else        { s = e - E_;        d = e - E_; }
    esrc[e] = s; edst[e] = d;
    atomicAdd(&icnt[d], 1);
    atomicAdd(&ocnt[s], 1);
  }
  __syncthreads();
  if (tid == 0) {
    int ai = 0, ao = 0;
    for (int n = 0; n < N_; ++n) {
      ibase[n] = ai; ai += icnt[n];
      obase[n] = ao; ao += ocnt[n];
    }
    ibase[N_] = ai; obase[N_] = ao;
  }
  __syncthreads();
  if (tid <= N_) { iOff_g[tid] = ibase[tid]; oOff_g[tid] = obase[tid]; }
  for (int e = tid; e < EP_; e += blockDim.x) {
    int s = esrc[e], d = edst[e];
    int pi = ibase[d] + atomicAdd(&ifill[d], 1);
    iSrc_g[pi] = s;
    int po = obase[s] + atomicAdd(&ofill[s], 1);
    oDst_g[po] = d;
  }
}

// ---- K1: a[b][tc][n][j][t32] = sum_c x[b][c][n][t]*wa[c][j] --------------------
// block = (b, t32-chunk, n-half); grid 256 x 1024. All x loads: 8 lanes x float4
// = full 128-B row per stream, 8 rows per instr, 8-deep batches. c split 4-way
// across thread groups, LDS pairwise reduce.
__global__ __launch_bounds__(1024, 1)
void proj_kernel(const float* __restrict__ x,
                 const float* __restrict__ wa_g,
                 float* __restrict__ a_ws) {
  __shared__ float wal[C_ * 8];
  __shared__ float bufA[8 * 32 * 40];   // [j][nl][40pad] 40 KB
  __shared__ float bufB[8 * 32 * 40];
  const int tid = threadIdx.x;
  const int b = blockIdx.x & 7;                // XCD pinning
  const int rest = blockIdx.x >> 3;
  const int tc = rest >> 1, nh = rest & 1;
  const int t0 = tc * TCK;

  for (int i = tid; i < C_ * 8; i += 1024) wal[i] = wa_g[i];
  __syncthreads();

  const int cs = tid >> 8;          // c-quarter 0..3
  const int nl = (tid >> 3) & 31;   // node-local 0..31
  const int q  = tid & 7;           // t-quad 0..7 (8 contiguous lanes = 128 B)
  const int n  = nh * 32 + nl;
  const float* xp = x + ((size_t)(b * C_ + cs * 32) * N_ + n) * T_ + t0 + q * 4;

  float4 acc[8];
#pragma unroll
  for (int j = 0; j < 8; ++j) { acc[j].x = 0.f; acc[j].y = 0.f; acc[j].z = 0.f; acc[j].w = 0.f; }
  for (int kb = 0; kb < 4; ++kb) {
    float4 xv[8];
#pragma unroll
    for (int u = 0; u < 8; ++u)
      xv[u] = *reinterpret_cast<const float4*>(xp + (size_t)(kb * 8 + u) * NT_);
#pragma unroll
    for (int u = 0; u < 8; ++u) {
      const int c = cs * 32 + kb * 8 + u;
      const float4 w0 = *reinterpret_cast<const float4*>(&wal[c * 8]);
      const float4 w1 = *reinterpret_cast<const float4*>(&wal[c * 8 + 4]);
      FMA4(acc[0], xv[u], w0.x) FMA4(acc[1], xv[u], w0.y)
      FMA4(acc[2], xv[u], w0.z) FMA4(acc[3], xv[u], w0.w)
      FMA4(acc[4], xv[u], w1.x) FMA4(acc[5], xv[u], w1.y)
      FMA4(acc[6], xv[u], w1.z) FMA4(acc[7], xv[u], w1.w)
    }
  }
  if (cs == 1) {
#pragma unroll
    for (int j = 0; j < 8; ++j)
      *reinterpret_cast<float4*>(&bufA[j * 1280 + nl * 40 + q * 4]) = acc[j];
  } else if (cs == 3) {
#pragma unroll
    for (int j = 0; j < 8; ++j)
      *reinterpret_cast<float4*>(&bufB[j * 1280 + nl * 40 + q * 4]) = acc[j];
  }
  __syncthreads();
  if (cs == 0) {
#pragma unroll
    for (int j = 0; j < 8; ++j) {
      float4 o = *reinterpret_cast<const float4*>(&bufA[j * 1280 + nl * 40 + q * 4]);
      acc[j].x += o.x; acc[j].y += o.y; acc[j].z += o.z; acc[j].w += o.w;
    }
  } else if (cs == 2) {
#pragma unroll
    for (int j = 0; j < 8; ++j) {
      float4 o = *reinterpret_cast<const float4*>(&bufB[j * 1280 + nl * 40 + q * 4]);
      acc[j].x += o.x; acc[j].y += o.y; acc[j].z += o.z; acc[j].w += o.w;
      *reinterpret_cast<float4*>(&bufB[j * 1280 + nl * 40 + q * 4]) = acc[j];
    }
  }
  __syncthreads();
  if (cs == 0) {
#pragma unroll
    for (int j = 0; j < 8; ++j) {
      float4 o = *reinterpret_cast<const float4*>(&bufB[j * 1280 + nl * 40 + q * 4]);
      acc[j].x += o.x; acc[j].y += o.y; acc[j].z += o.z; acc[j].w += o.w;
      *reinterpret_cast<float4*>(
          &a_ws[((((size_t)(b * 16 + tc)) * 64 + n) * 8 + j) * 32 + q * 4]) = acc[j];
    }
  }
}

// ---- K2': softmax (recomputed per c-half, cheap) + aggregation ----------------
// block = (b, t32-chunk, c-half); grid 256 x 1024. x loads: 128-B rows, 8-deep.
// y[b][h][c][t] written to ws for the tiny K3 epilogue.
__global__ __launch_bounds__(1024, 1)
void agg_kernel(const float* __restrict__ x,
                const float* __restrict__ a_ws,
                const int* __restrict__ iOff_g, const int* __restrict__ iSrc_g,
                const int* __restrict__ oOff_g, const int* __restrict__ oDst_g,
                float* __restrict__ y_ws) {
  __shared__ float a_l[64 * 8 * 36];   // [n][j][36pad] 73.7 KB; scr alias later
  __shared__ float z_l[64 * 4 * 36];   // [nd][h][36pad] 36.9 KB
  __shared__ float w_l[64 * 4 * 36];   // [n][h][36pad] 36.9 KB
  __shared__ int iSrc[EP_], oDst[EP_];
  __shared__ int iOff[N_ + 1], oOff[N_ + 1];
  const int tid = threadIdx.x;
  const int b = blockIdx.x & 7;
  const int rest = blockIdx.x >> 3;
  const int tc = rest >> 1, ch = rest & 1;
  const int t0 = tc * TCK;

  if (tid < EP_) { iSrc[tid] = iSrc_g[tid]; oDst[tid] = oDst_g[tid]; }
  else if (tid < EP_ + N_ + 1) {
    int i = tid - EP_;
    iOff[i] = iOff_g[i]; oOff[i] = oOff_g[i];
  }
  {
    const float4* src = reinterpret_cast<const float4*>(
        a_ws + (size_t)(b * 16 + tc) * (64 * 8 * 32));
#pragma unroll
    for (int f = 0; f < 4; ++f) {
      int g = f * 1024 + tid;
      int nn = g >> 6, j = (g >> 3) & 7, q = g & 7;
      *reinterpret_cast<float4*>(&a_l[nn * 288 + j * 36 + q * 4]) = src[g];
    }
  }
  __syncthreads();

  // softmax B: per (dst,t): z = exp(-m)/(den*N)
  {
    const int t = tid & 31, g = tid >> 5;
#pragma unroll
    for (int rep = 0; rep < 2; ++rep) {
      int nd = g + rep * 32;
      int e0 = iOff[nd], e1 = iOff[nd + 1];
      float ad0 = a_l[nd * 288 + 4 * 36 + t];
      float ad1 = a_l[nd * 288 + 5 * 36 + t];
      float ad2 = a_l[nd * 288 + 6 * 36 + t];
      float ad3 = a_l[nd * 288 + 7 * 36 + t];
      float m0 = -1e30f, m1 = -1e30f, m2 = -1e30f, m3 = -1e30f;
      for (int e = e0; e < e1; ++e) {
        int s = iSrc[e];
        float v0 = a_l[s * 288 + 0 * 36 + t] + ad0; v0 = v0 > 0.f ? v0 : NEG_SLOPE * v0;
        float v1 = a_l[s * 288 + 1 * 36 + t] + ad1; v1 = v1 > 0.f ? v1 : NEG_SLOPE * v1;
        float v2 = a_l[s * 288 + 2 * 36 + t] + ad2; v2 = v2 > 0.f ? v2 : NEG_SLOPE * v2;
        float v3 = a_l[s * 288 + 3 * 36 + t] + ad3; v3 = v3 > 0.f ? v3 : NEG_SLOPE * v3;
        m0 = fmaxf(m0, v0); m1 = fmaxf(m1, v1);
        m2 = fmaxf(m2, v2); m3 = fmaxf(m3, v3);
      }
      float d0 = 0.f, d1 = 0.f, d2 = 0.f, d3 = 0.f;
      for (int e = e0; e < e1; ++e) {
        int s = iSrc[e];
        float v0 = a_l[s * 288 + 0 * 36 + t] + ad0; v0 = v0 > 0.f ? v0 : NEG_SLOPE * v0;
        float v1 = a_l[s * 288 + 1 * 36 + t] + ad1; v1 = v1 > 0.f ? v1 : NEG_SLOPE * v1;
        float v2 = a_l[s * 288 + 2 * 36 + t] + ad2; v2 = v2 > 0.f ? v2 : NEG_SLOPE * v2;
        float v3 = a_l[s * 288 + 3 * 36 + t] + ad3; v3 = v3 > 0.f ? v3 : NEG_SLOPE * v3;
        d0 += __expf(v0 - m0); d1 += __expf(v1 - m1);
        d2 += __expf(v2 - m2); d3 += __expf(v3 - m3);
      }
      z_l[nd * 144 + 0 * 36 + t] = __expf(-m0) / (d0 * (float)N_);
      z_l[nd * 144 + 1 * 36 + t] = __expf(-m1) / (d1 * (float)N_);
      z_l[nd * 144 + 2 * 36 + t] = __expf(-m2) / (d2 * (float)N_);
      z_l[nd * 144 + 3 * 36 + t] = __expf(-m3) / (d3 * (float)N_);
    }
  }
  __syncthreads();

  // softmax C: per (src,t) gather -> w_l[n][h][t]
  {
    const int t = tid & 31, g = tid >> 5;
#pragma unroll
    for (int rep = 0; rep < 2; ++rep) {
      int src = g + rep * 32;
      int e0 = oOff[src], e1 = oOff[src + 1];
      float as0 = a_l[src * 288 + 0 * 36 + t];
      float as1 = a_l[src * 288 + 1 * 36 + t];
      float as2 = a_l[src * 288 + 2 * 36 + t];
      float as3 = a_l[src * 288 + 3 * 36 + t];
      float w0 = 0.f, w1 = 0.f, w2 = 0.f, w3 = 0.f;
      for (int e = e0; e < e1; ++e) {
        int d = oDst[e];
        float z0 = z_l[d * 144 + 0 * 36 + t];
        float z1 = z_l[d * 144 + 1 * 36 + t];
        float z2 = z_l[d * 144 + 2 * 36 + t];
        float z3 = z_l[d * 144 + 3 * 36 + t];
        float v0 = as0 + a_l[d * 288 + 4 * 36 + t]; v0 = v0 > 0.f ? v0 : NEG_SLOPE * v0;
        float v1 = as1 + a_l[d * 288 + 5 * 36 + t]; v1 = v1 > 0.f ? v1 : NEG_SLOPE * v1;
        float v2 = as2 + a_l[d * 288 + 6 * 36 + t]; v2 = v2 > 0.f ? v2 : NEG_SLOPE * v2;
        float v3 = as3 + a_l[d * 288 + 7 * 36 + t]; v3 = v3 > 0.f ? v3 : NEG_SLOPE * v3;
        w0 += __expf(v0) * z0;
        w1 += __expf(v1) * z1;
        w2 += __expf(v2) * z2;
        w3 += __expf(v3) * z3;
      }
      w_l[src * 144 + 0 * 36 + t] = w0;
      w_l[src * 144 + 1 * 36 + t] = w1;
      w_l[src * 144 + 2 * 36 + t] = w2;
      w_l[src * 144 + 3 * 36 + t] = w3;
    }
  }
  __syncthreads();

  // aggregation: y[h][c][t] = sum_n w[n][h][t] * x[b][c][n][t]
  {
    const int c  = tid >> 4;          // 0..63 (c-half local)
    const int q  = (tid >> 1) & 7;    // t-quad
    const int ns = tid & 1;           // n-half split
    const float* xp = x + ((size_t)(b * C_ + ch * 64 + c) * N_ + ns * 32) * T_ + t0 + q * 4;
    float4 yr[4];
#pragma unroll
    for (int h = 0; h < 4; ++h) { yr[h].x = 0.f; yr[h].y = 0.f; yr[h].z = 0.f; yr[h].w = 0.f; }
    for (int ib = 0; ib < 4; ++ib) {
      float4 xv[8];
#pragma unroll
      for (int u = 0; u < 8; ++u)
        xv[u] = *reinterpret_cast<const float4*>(xp + (size_t)(ib * 8 + u) * T_);
#pragma unroll
      for (int u = 0; u < 8; ++u) {
        const int n = ns * 32 + ib * 8 + u;
#pragma unroll
        for (int h = 0; h < 4; ++h) {
          float4 wv = *reinterpret_cast<const float4*>(&w_l[n * 144 + h * 36 + q * 4]);
          yr[h].x = fmaf(xv[u].x, wv.x, yr[h].x);
          yr[h].y = fmaf(xv[u].y, wv.y, yr[h].y);
          yr[h].z = fmaf(xv[u].z, wv.z, yr[h].z);
          yr[h].w = fmaf(xv[u].w, wv.w, yr[h].w);
        }
      }
    }
    float* scr = a_l;   // a_l dead after softmax C
    if (ns == 1) {
#pragma unroll
      for (int h = 0; h < 4; ++h)
        *reinterpret_cast<float4*>(&scr[c * 144 + h * 36 + q * 4]) = yr[h];
    }
    __syncthreads();
    if (ns == 0) {
#pragma unroll
      for (int h = 0; h < 4; ++h) {
        float4 o = *reinterpret_cast<const float4*>(&scr[c * 144 + h * 36 + q * 4]);
        yr[h].x += o.x; yr[h].y += o.y; yr[h].z += o.z; yr[h].w += o.w;
        *reinterpret_cast<float4*>(
            &y_ws[(((size_t)(b * 4 + h) * 128) + ch * 64 + c) * 512 + t0 + q * 4]) = yr[h];
      }
    }
  }
}

// ---- K3: out = BN(y·W + bias); grid = B*H*(T/64) = 256, block = 256 ------------
__global__ void out_kernel(const float* __restrict__ y_ws,
                           const float* __restrict__ W,
                           const float* __restrict__ bias,
                           const float* __restrict__ bn_gamma,
                           const float* __restrict__ bn_beta,
                           const float* __restrict__ bn_mean,
                           const float* __restrict__ bn_var,
                           float* __restrict__ out) {
  __shared__ float wl[C_ * D_];   // W[:,h,:] 16 KB
  int blk = blockIdx.x;
  int b = blk & 7;
  int h = (blk >> 3) & 3;
  int tcb = blk >> 5;
  int tid = threadIdx.x;
  int t = tcb * 64 + (tid & 63);
  int d0 = (tid >> 6) * 8;
  for (int i = tid; i < C_ * D_; i += 256) {
    int c = i >> 5, d = i & 31;
    wl[i] = W[((size_t)c * H_ + h) * D_ + d];
  }
  __syncthreads();
  float acc[8] = {0.f, 0.f, 0.f, 0.f, 0.f, 0.f, 0.f, 0.f};
  const float* yp = y_ws + ((size_t)b * H_ + h) * C_ * T_ + t;
#pragma unroll 4
  for (int c = 0; c < C_; ++c) {
    float yv = yp[(size_t)c * T_];
    const float4 w0 = *reinterpret_cast<const float4*>(&wl[c * D_ + d0]);
    const float4 w1 = *reinterpret_cast<const float4*>(&wl[c * D_ + d0 + 4]);
    acc[0] = fmaf(yv, w0.x, acc[0]); acc[1] = fmaf(yv, w0.y, acc[1]);
    acc[2] = fmaf(yv, w0.z, acc[2]); acc[3] = fmaf(yv, w0.w, acc[3]);
    acc[4] = fmaf(yv, w1.x, acc[4]); acc[5] = fmaf(yv, w1.y, acc[5]);
    acc[6] = fmaf(yv, w1.z, acc[6]); acc[7] = fmaf(yv, w1.w, acc[7]);
  }
#pragma unroll
  for (int k = 0; k < 8; ++k) {
    int oc = h * D_ + d0 + k;
    float scale = bn_gamma[oc] * rsqrtf(bn_var[oc] + BN_EPS);
    float shift = bn_beta[oc] - bn_mean[oc] * scale;
    out[((size_t)b * OUT_ + oc) * T_ + t] = (acc[k] + bias[oc]) * scale + shift;
  }
}

extern "C" void kernel_launch(void* const* d_in, const int* in_sizes, int n_in,
                              void* d_out, int out_size, void* d_ws, size_t ws_size,
                              hipStream_t stream) {
  const float* x        = (const float*)d_in[0];
  const float* W        = (const float*)d_in[1];
  const float* att_src  = (const float*)d_in[2];
  const float* att_dst  = (const float*)d_in[3];
  const float* bias     = (const float*)d_in[4];
  const float* bn_gamma = (const float*)d_in[5];
  const float* bn_beta  = (const float*)d_in[6];
  const float* bn_mean  = (const float*)d_in[7];
  const float* bn_var   = (const float*)d_in[8];
  const int* edge_index = (const int*)d_in[9];
  float* out = (float*)d_out;

  char* ws = (char*)d_ws;
  float* wa   = (float*)ws;            // 4 KB
  int* iOff_g = (int*)(ws + 4096);     // 65 ints
  int* iSrc_g = (int*)(ws + 4608);     // 320 ints
  int* oOff_g = (int*)(ws + 6144);     // 65 ints
  int* oDst_g = (int*)(ws + 6656);     // 320 ints
  float* a_ws = (float*)(ws + 16384);                               // 8 MB [b][tc][n][j][t32]
  float* y_ws = (float*)(ws + 16384 + (size_t)8 * 1024 * 1024);     // 8 MB [b][h][c][t]

  setup_kernel<<<1, 256, 0, stream>>>(W, att_src, att_dst, edge_index, wa,
                                      iOff_g, iSrc_g, oOff_g, oDst_g);
  proj_kernel<<<256, 1024, 0, stream>>>(x, wa, a_ws);
  agg_kernel<<<256, 1024, 0, stream>>>(x, a_ws, iOff_g, iSrc_g, oOff_g, oDst_g,
                                       y_ws);
  out_kernel<<<256, 256, 0, stream>>>(y_ws, W, bias, bn_gamma, bn_beta,
                                      bn_mean, bn_var, out);
}